// Round 12
// baseline (278.342 us; speedup 1.0000x reference)
//
#include <hip/hip_runtime.h>

#define NN 100000
#define NE 1600000
#define DD 128
#define BN_EPS 1e-5f

#define SBSH 9                         // log2(super-bucket size)
#define SBSZ 512                       // nodes per super-bucket
#define NSB ((NN + SBSZ - 1) / SBSZ)   // 196 super-buckets
#define CAPS 9216                      // slots per bucket (mean 8163 + ~11 sigma)
#define SCATBLKS 512                   // scatter-role blocks (R11-proven)
#define EPB ((NE + SCATBLKS - 1) / SCATBLKS)   // 3125 edges/block; chunk ~16 ints
#define PREPBLKS 512
#define GRID_PS (SCATBLKS + PREPBLKS)  // 1024
#define QCAP 3072                      // es capacity per 128-node quarter (mean 2048, +22 sigma)
#define BN_BLOCKS 1024

typedef __attribute__((ext_vector_type(8))) short short8;
typedef __attribute__((ext_vector_type(4))) float floatx4;

__device__ __forceinline__ unsigned short f2bf(float f) {
    union { float f; unsigned u; } v; v.f = f;
    return (unsigned short)((v.u + 0x7FFFu + ((v.u >> 16) & 1u)) >> 16);
}
__device__ __forceinline__ float bf2f(unsigned short u) {
    union { unsigned u; float f; } v; v.u = ((unsigned)u) << 16;
    return v.f;
}

// ---------------------------------------------------------------------------
// K1 (fused, R11-proven): blocks [0,512) = super-bucket radix scatter
// (chunk-reserved direct scatter; ~16-int chunks); blocks [512,1024) = prep
// (W->bf16 transpose + h->bf16 copy). scnt zeroed by preceding memset.
// ---------------------------------------------------------------------------
__global__ __launch_bounds__(256) void prep_scatter_kernel(
    const float* __restrict__ W1, const float* __restrict__ W2,
    unsigned short* __restrict__ W1t, unsigned short* __restrict__ W2t,
    const float* __restrict__ h, unsigned short* __restrict__ hb, int do_hb,
    const int* __restrict__ src, const int* __restrict__ dst,
    int* __restrict__ scnt, int* __restrict__ sbuf)
{
    __shared__ int bins[256];
    int t = threadIdx.x;

    if (blockIdx.x < SCATBLKS) {
        bins[t] = 0;
        __syncthreads();
        int base = blockIdx.x * EPB;
        int ecnt = min(EPB, NE - base);
        for (int i = t; i < ecnt; i += 256)
            atomicAdd(&bins[dst[base + i] >> SBSH], 1);
        __syncthreads();
        int c = bins[t];
        int gb = (t < NSB && c) ? atomicAdd(&scnt[t], c) : 0;
        __syncthreads();
        bins[t] = t * CAPS + gb;   // global chunk cursor for this block
        __syncthreads();
        for (int i = t; i < ecnt; i += 256) {
            int d = dst[base + i];
            int p = atomicAdd(&bins[d >> SBSH], 1);
            sbuf[p] = (src[base + i] << SBSH) | (d & (SBSZ - 1));
        }
    } else {
        int tid0 = (blockIdx.x - SCATBLKS) * 256 + t;
        int stride = PREPBLKS * 256;
        for (int i = tid0; i < DD * DD; i += stride) {
            int n = i >> 7, k = i & 127;
            W1t[i] = f2bf(W1[k * DD + n]);
            W2t[i] = f2bf(W2[k * DD + n]);
        }
        if (do_hb) {
            const float4* h4 = (const float4*)h;
            ushort4* hb4 = (ushort4*)hb;
            for (int i = tid0; i < NN * (DD / 4); i += stride) {
                float4 v = h4[i];
                ushort4 o;
                o.x = f2bf(v.x); o.y = f2bf(v.y); o.z = f2bf(v.z); o.w = f2bf(v.w);
                hb4[i] = o;
            }
        }
    }
}

// ---------------------------------------------------------------------------
// K2 (fused permute+gather): 4 sub-blocks per super-bucket (784 blocks,
// 256 thr, ~14KB LDS -> ~3 blocks/CU = 12 waves/CU across ALL 256 CUs).
// Each sub-block filters its 128-node quarter out of the bucket's edge list
// (2 passes over the L2-resident sbuf region), builds its per-node CSR in
// LDS (es), then gathers. Deletes the old K2 dispatch, its 8MB permuted-
// sbuf/off2 round-trip, and one graph boundary. R3 evidence: gather is
// bandwidth-bound (~3.6TB/s) above ~25% occ, so the occupancy drop vs the
// standalone gather costs only ~+8us.
// ---------------------------------------------------------------------------
template <bool HB>
__global__ __launch_bounds__(256) void permgather_kernel(
    const float* __restrict__ h, const unsigned short* __restrict__ hb,
    const float* __restrict__ eps, const int* __restrict__ scnt,
    const int* __restrict__ sbuf, unsigned short* __restrict__ xb)
{
    __shared__ int es[QCAP];          // 12288 B: this quarter's srcs, CSR order
    __shared__ int cnt[128];
    __shared__ int beg[128];
    __shared__ int cur[128];

    const int sub = blockIdx.x;
    const int b = sub >> 2;           // super-bucket
    const int q = sub & 3;            // 128-node quarter within bucket
    const int t = threadIdx.x;

    if (t < 128) cnt[t] = 0;
    __syncthreads();

    const int n = min(scnt[b], CAPS);
    const int sbase = b * CAPS;

    // pass 1: count this quarter's edges per node
    for (int i = t; i < n; i += 256) {
        int e = sbuf[sbase + i];
        int nl = e & (SBSZ - 1);
        if ((nl >> 7) == q) atomicAdd(&cnt[nl & 127], 1);
    }
    __syncthreads();

    // exclusive scan over 128 node bins
    if (t < 128) beg[t] = cnt[t];
    __syncthreads();
#pragma unroll
    for (int ofs = 1; ofs < 128; ofs <<= 1) {
        int u = (t < 128 && t >= ofs) ? beg[t - ofs] : 0;
        __syncthreads();
        if (t < 128) beg[t] += u;
        __syncthreads();
    }
    if (t < 128) {
        int ex = beg[t] - cnt[t];
        beg[t] = ex;
        cur[t] = ex;
    }
    __syncthreads();

    // pass 2: collect this quarter's srcs into LDS CSR
    for (int i = t; i < n; i += 256) {
        int e = sbuf[sbase + i];
        int nl = e & (SBSZ - 1);
        if ((nl >> 7) == q) {
            int p = atomicAdd(&cur[nl & 127], 1);
            es[p] = e >> SBSH;
        }
    }
    __syncthreads();

    // gather: 16 lanes/node, 16 nodes/pass, 8 passes
    const float sE = 1.0f + eps[0];
    const float4* h4 = (const float4*)h;
    const short8* hb8 = (const short8*)hb;
    const int c8 = t & 15;
    const int node0 = b * SBSZ + (q << 7);
#pragma unroll
    for (int pass = 0; pass < 8; ++pass) {
        int nl = pass * 16 + (t >> 4);
        int node = node0 + nl;
        if (node >= NN) continue;
        float4 a0 = h4[node * 32 + c8 * 2];
        float4 a1 = h4[node * 32 + c8 * 2 + 1];
        float acc[8] = {sE * a0.x, sE * a0.y, sE * a0.z, sE * a0.w,
                        sE * a1.x, sE * a1.y, sE * a1.z, sE * a1.w};
        int e = beg[nl], eend = beg[nl] + cnt[nl];
        if (HB) {
            for (; e + 3 < eend; e += 4) {
                int s0 = es[e],     s1 = es[e + 1];
                int s2 = es[e + 2], s3 = es[e + 3];
                short8 v0 = hb8[s0 * 16 + c8];
                short8 v1 = hb8[s1 * 16 + c8];
                short8 v2 = hb8[s2 * 16 + c8];
                short8 v3 = hb8[s3 * 16 + c8];
#pragma unroll
                for (int j = 0; j < 8; ++j) {
                    float t0 = bf2f((unsigned short)v0[j]) + bf2f((unsigned short)v1[j]);
                    float t1 = bf2f((unsigned short)v2[j]) + bf2f((unsigned short)v3[j]);
                    acc[j] += t0 + t1;
                }
            }
            for (; e < eend; ++e) {
                short8 v0 = hb8[es[e] * 16 + c8];
#pragma unroll
                for (int j = 0; j < 8; ++j) acc[j] += bf2f((unsigned short)v0[j]);
            }
        } else {
            for (; e + 1 < eend; e += 2) {
                int s0 = es[e], s1 = es[e + 1];
                float4 u0 = h4[s0 * 32 + c8 * 2], u1 = h4[s0 * 32 + c8 * 2 + 1];
                float4 w0 = h4[s1 * 32 + c8 * 2], w1 = h4[s1 * 32 + c8 * 2 + 1];
                acc[0] += u0.x + w0.x; acc[1] += u0.y + w0.y;
                acc[2] += u0.z + w0.z; acc[3] += u0.w + w0.w;
                acc[4] += u1.x + w1.x; acc[5] += u1.y + w1.y;
                acc[6] += u1.z + w1.z; acc[7] += u1.w + w1.w;
            }
            if (e < eend) {
                int s0 = es[e];
                float4 u0 = h4[s0 * 32 + c8 * 2], u1 = h4[s0 * 32 + c8 * 2 + 1];
                acc[0] += u0.x; acc[1] += u0.y; acc[2] += u0.z; acc[3] += u0.w;
                acc[4] += u1.x; acc[5] += u1.y; acc[6] += u1.z; acc[7] += u1.w;
            }
        }
        short8 o;
#pragma unroll
        for (int j = 0; j < 8; ++j) o[j] = (short)f2bf(acc[j]);
        ((short8*)xb)[node * 16 + c8] = o;
    }
}

// ---------------------------------------------------------------------------
// K3: fused 2-layer MLP + BN stats, 128-row / 512-thread tile (R10/R11-
// proven). W staged once per layer per 128 rows.
// ---------------------------------------------------------------------------
__global__ __launch_bounds__(512) void mlp_fused_kernel(
    const unsigned short* __restrict__ X,
    const unsigned short* __restrict__ W1t, const unsigned short* __restrict__ W2t,
    const float* __restrict__ b1, const float* __restrict__ b2,
    unsigned short* __restrict__ Y, float* __restrict__ stats)
{
    extern __shared__ char smem[];
    unsigned short* wl = (unsigned short*)smem;            // [128][136] bf16
    unsigned short* xl = (unsigned short*)(smem + 34816);  // [128][136] bf16

    const int tid = threadIdx.x;
    const int r0 = blockIdx.x * 128;
    const int lane = tid & 63;
    const int wv = tid >> 6;        // 0..7: wave's 16-row band
    const int m = lane & 15;
    const int hi = lane >> 4;

    const short8* W18 = (const short8*)W1t;
#pragma unroll
    for (int l = 0; l < 4; ++l) {
        int idx = tid + l * 512;
        int n = idx >> 4, c = idx & 15;
        *(short8*)&wl[n * 136 + c * 8] = W18[idx];
    }
    const short8* X8 = (const short8*)X;
#pragma unroll
    for (int l = 0; l < 4; ++l) {
        int idx = tid + l * 512;
        int row = idx >> 4, c = idx & 15;
        int g = r0 + row;
        short8 v = {0, 0, 0, 0, 0, 0, 0, 0};
        if (g < NN) v = X8[g * 16 + c];
        *(short8*)&xl[row * 136 + c * 8] = v;
    }
    __syncthreads();

    floatx4 acc[8];
#pragma unroll
    for (int i = 0; i < 8; ++i) acc[i] = (floatx4){0.f, 0.f, 0.f, 0.f};
#pragma unroll
    for (int kc = 0; kc < 4; ++kc) {
        short8 a = *(const short8*)&xl[(wv * 16 + m) * 136 + kc * 32 + hi * 8];
#pragma unroll
        for (int nt = 0; nt < 8; ++nt) {
            short8 b = *(const short8*)&wl[(nt * 16 + m) * 136 + kc * 32 + hi * 8];
            acc[nt] = __builtin_amdgcn_mfma_f32_16x16x32_bf16(a, b, acc[nt], 0, 0, 0);
        }
    }
    __syncthreads();

#pragma unroll
    for (int nt = 0; nt < 8; ++nt) {
        float bv = b1[nt * 16 + m];
#pragma unroll
        for (int r = 0; r < 4; ++r) {
            float v = fmaxf(acc[nt][r] + bv, 0.f);
            xl[(wv * 16 + hi * 4 + r) * 136 + nt * 16 + m] = f2bf(v);
        }
    }
    const short8* W28 = (const short8*)W2t;
#pragma unroll
    for (int l = 0; l < 4; ++l) {
        int idx = tid + l * 512;
        int n = idx >> 4, c = idx & 15;
        *(short8*)&wl[n * 136 + c * 8] = W28[idx];
    }
    __syncthreads();

#pragma unroll
    for (int i = 0; i < 8; ++i) acc[i] = (floatx4){0.f, 0.f, 0.f, 0.f};
#pragma unroll
    for (int kc = 0; kc < 4; ++kc) {
        short8 a = *(const short8*)&xl[(wv * 16 + m) * 136 + kc * 32 + hi * 8];
#pragma unroll
        for (int nt = 0; nt < 8; ++nt) {
            short8 b = *(const short8*)&wl[(nt * 16 + m) * 136 + kc * 32 + hi * 8];
            acc[nt] = __builtin_amdgcn_mfma_f32_16x16x32_bf16(a, b, acc[nt], 0, 0, 0);
        }
    }
    __syncthreads();

#pragma unroll
    for (int nt = 0; nt < 8; ++nt) {
        float bv = b2[nt * 16 + m];
#pragma unroll
        for (int r = 0; r < 4; ++r) {
            float v = acc[nt][r] + bv;
            xl[(wv * 16 + hi * 4 + r) * 136 + nt * 16 + m] = f2bf(v);
        }
    }
    __syncthreads();

#pragma unroll
    for (int l = 0; l < 4; ++l) {
        int idx = tid + l * 512;
        int row = idx >> 4, c = idx & 15;
        int g = r0 + row;
        if (g < NN)
            ((short8*)Y)[g * 16 + c] = *(const short8*)&xl[row * 136 + c * 8];
    }

    int col = tid & 127, quarter = tid >> 7;
    int rlim = min(128, NN - r0);
    int rbeg = quarter * 32, rend = min(rbeg + 32, rlim);
    float s = 0.f, q = 0.f;
    for (int r = rbeg; r < rend; ++r) {
        float v = bf2f(xl[r * 136 + col]);
        s += v; q += v * v;
    }
    float* red = (float*)wl;        // wl dead after GEMM2
    red[tid] = s;
    red[512 + tid] = q;
    __syncthreads();
    if (tid < 128) {
        float ts = red[tid] + red[128 + tid] + red[256 + tid] + red[384 + tid];
        float tq = red[512 + tid] + red[640 + tid] + red[768 + tid] + red[896 + tid];
        atomicAdd(&stats[tid], ts);
        atomicAdd(&stats[DD + tid], tq);
    }
}

// ---------------------------------------------------------------------------
// K4: out = h + relu(Y*scale + shift). BN math hoisted (column octet fixed).
// ---------------------------------------------------------------------------
__global__ __launch_bounds__(256) void bn_final_kernel(
    const unsigned short* __restrict__ Y, const float* __restrict__ h,
    const float* __restrict__ gamma, const float* __restrict__ beta,
    const float* __restrict__ stats, float* __restrict__ out)
{
    const float invN = 1.0f / (float)NN;
    int t0 = blockIdx.x * 256 + threadIdx.x;
    int c8 = t0 & 15;
    float sc[8], sh[8];
#pragma unroll
    for (int j = 0; j < 8; ++j) {
        int col = c8 * 8 + j;
        float mu = stats[col] * invN;
        float var = stats[DD + col] * invN - mu * mu;
        float s = rsqrtf(var + BN_EPS) * gamma[col];
        sc[j] = s;
        sh[j] = beta[col] - mu * s;
    }
    const short8* Y8 = (const short8*)Y;
    const float4* H4 = (const float4*)h;
    float4* O4 = (float4*)out;
    const int total = NN * 16;
    const int stride = BN_BLOCKS * 256;
    for (int i = t0; i < total; i += stride) {
        short8 u = Y8[i];
        float4 h0 = H4[2 * i], h1 = H4[2 * i + 1];
        float4 r0, r1;
        r0.x = h0.x + fmaxf(bf2f((unsigned short)u[0]) * sc[0] + sh[0], 0.f);
        r0.y = h0.y + fmaxf(bf2f((unsigned short)u[1]) * sc[1] + sh[1], 0.f);
        r0.z = h0.z + fmaxf(bf2f((unsigned short)u[2]) * sc[2] + sh[2], 0.f);
        r0.w = h0.w + fmaxf(bf2f((unsigned short)u[3]) * sc[3] + sh[3], 0.f);
        r1.x = h1.x + fmaxf(bf2f((unsigned short)u[4]) * sc[4] + sh[4], 0.f);
        r1.y = h1.y + fmaxf(bf2f((unsigned short)u[5]) * sc[5] + sh[5], 0.f);
        r1.z = h1.z + fmaxf(bf2f((unsigned short)u[6]) * sc[6] + sh[6], 0.f);
        r1.w = h1.w + fmaxf(bf2f((unsigned short)u[7]) * sc[7] + sh[7], 0.f);
        O4[2 * i] = r0;
        O4[2 * i + 1] = r1;
    }
}

// ---------------------------------------------------------------------------
extern "C" void kernel_launch(void* const* d_in, const int* in_sizes, int n_in,
                              void* d_out, int out_size, void* d_ws, size_t ws_size,
                              hipStream_t stream)
{
    const float* h     = (const float*)d_in[0];
    const int*   src   = (const int*)d_in[1];
    const int*   dst   = (const int*)d_in[2];
    const float* eps   = (const float*)d_in[3];
    const float* W1    = (const float*)d_in[4];
    const float* b1    = (const float*)d_in[5];
    const float* W2    = (const float*)d_in[6];
    const float* b2    = (const float*)d_in[7];
    const float* gamma = (const float*)d_in[8];
    const float* beta  = (const float*)d_in[9];
    float* out = (float*)d_out;

    char* w = (char*)d_ws;
    size_t o = 0;
    float* stats    = (float*)(w + o); o += 256 * 4;                 // memset
    int* scnt       = (int*)(w + o); o += 256 * 4;                   // memset
    unsigned short* W1t = (unsigned short*)(w + o); o += (size_t)DD * DD * 2;
    unsigned short* W2t = (unsigned short*)(w + o); o += (size_t)DD * DD * 2;
    int* sbuf       = (int*)(w + o); o += (size_t)NSB * CAPS * 4;    // 7.2 MB
    unsigned short* xb  = (unsigned short*)(w + o); o += (size_t)NN * DD * 2;
    unsigned short* hb  = (unsigned short*)(w + o); o += (size_t)NN * DD * 2;
    const int use_hb = (ws_size >= o) ? 1 : 0;  // launch-constant

    // 0. zero stats + super-bucket cursors
    hipMemsetAsync(stats, 0, 512 * sizeof(int), stream);

    // 1. fused prep + radix scatter (512 scatter + 512 prep blocks)
    prep_scatter_kernel<<<GRID_PS, 256, 0, stream>>>(
        W1, W2, W1t, W2t, h, hb, use_hb, src, dst, scnt, sbuf);

    // 2. fused per-quarter CSR permute + gather (K2 dispatch deleted)
    if (use_hb)
        permgather_kernel<true><<<NSB * 4, 256, 0, stream>>>(h, hb, eps, scnt, sbuf, xb);
    else
        permgather_kernel<false><<<NSB * 4, 256, 0, stream>>>(h, hb, eps, scnt, sbuf, xb);

    // 3. fused 2-layer MLP + BN stats (128-row / 512-thread tile)
    size_t gemm_lds = 69632;
    mlp_fused_kernel<<<(NN + 127) / 128, 512, gemm_lds, stream>>>(
        xb, W1t, W2t, b1, b2, xb, stats);

    // 4. out = h + relu(BN(y2))
    bn_final_kernel<<<BN_BLOCKS, 256, 0, stream>>>(xb, h, gamma, beta, stats, out);
}